// Round 9
// baseline (1325.446 us; speedup 1.0000x reference)
//
#include <hip/hip_runtime.h>
#include <hip/hip_bf16.h>
#include <cstdint>

typedef __hip_bfloat16 bf16;
#define DEVI __device__ __forceinline__

DEVI float b2f(bf16 v){ return __bfloat162float(v); }
DEVI bf16 f2b(float v){ return __float2bfloat16(v); }
DEVI float lrelu(float x, float s){ return x > 0.f ? x : x * s; }

// dtype-adaptive accessors: f==1 -> bf16 data, f==0 -> float32 data
DEVI float ldf(const void* p, size_t i, int f){
  return f ? b2f(((const bf16*)p)[i]) : ((const float*)p)[i];
}
DEVI void stf(void* p, size_t i, int f, float v){
  if(f) ((bf16*)p)[i] = f2b(v); else ((float*)p)[i] = v;
}

DEVI float wave_sum(float v){
#pragma unroll
  for(int o = 32; o > 0; o >>= 1) v += __shfl_xor(v, o, 64);
  return v;
}
// sum within 16-lane quarter (4 quarters reduce simultaneously)
DEVI float qsum(float v){
  v += __shfl_xor(v, 1, 64);
  v += __shfl_xor(v, 2, 64);
  v += __shfl_xor(v, 4, 64);
  v += __shfl_xor(v, 8, 64);
  return v;
}

// ---- dtype detector ---------------------------------------------------------
__global__ void k_detect(const uint32_t* __restrict__ xf, int* flag){
  const int lane = threadIdx.x & 63;
  float cnt = 0.f;
  for(int i = lane; i < 256; i += 64){
    uint32_t e = (xf[i] >> 7) & 0xFF;
    if(e >= 100 && e <= 140) cnt += 1.f;
  }
  cnt = wave_sum(cnt);
  if(lane == 0 && blockIdx.x == 0) *flag = (cnt > 180.f) ? 1 : 0;
}

// ---- encoder ----------------------------------------------------------------
__global__ __launch_bounds__(256) void k_encoder(
    const void* __restrict__ xf, const int* __restrict__ ids,
    const void* __restrict__ emb, const void* __restrict__ win,
    const void* __restrict__ bin, float* __restrict__ x,
    const int* __restrict__ flagp, int N)
{
  __shared__ float W[128*64];
  __shared__ float B[64];
  __shared__ float XR[4][128];
  const int t = threadIdx.x;
  const int f = *flagp;
  for(int i = t; i < 128*64; i += 256) W[i] = ldf(win, i, f);
  if(t < 64) B[t] = ldf(bin, t, f);
  __syncthreads();
  const int w = t >> 6, lane = t & 63;
  for(int base = blockIdx.x*4; base < N; base += gridDim.x*4){
    const int node = base + w;
    if(node < N){
      for(int k = lane; k < 128; k += 64){
        float v;
        if(k < 124) v = ldf(xf, (size_t)node*124 + k, f);
        else        v = ldf(emb, (size_t)ids[node]*4 + (k-124), f);
        XR[w][k] = v;
      }
      float acc = B[lane];
#pragma unroll 8
      for(int k = 0; k < 128; k++) acc = fmaf(XR[w][k], W[k*64+lane], acc);
      x[(size_t)node*64 + lane] = lrelu(acc, 0.01f);
    }
  }
}

// ---- per-layer linear, with layer-(l-1) GraphNorm fused in -----------------
// W column held in 64 VGPRs (hoisted once); XR read via broadcast float4.
__global__ __launch_bounds__(256) void k_linear(
    const float* __restrict__ x, const void* __restrict__ lw,
    const void* __restrict__ lb, float* __restrict__ g,
    const float* __restrict__ stats, const void* __restrict__ gw,
    const void* __restrict__ gb, const void* __restrict__ gms,
    void* __restrict__ out, const float* __restrict__ acsr,
    const int* __restrict__ pos, size_t h_base, size_t alpha_base,
    const int* __restrict__ flagp, int layer, int N, int T, float invN)
{
  __shared__ float W[64*64];
  __shared__ float B[64];
  __shared__ float XR[4][64];
  const int t = threadIdx.x;
  const int f = *flagp;
  const size_t wofs = (size_t)layer*64*64, bofs = (size_t)layer*64;
  for(int i = t; i < 64*64; i += 256) W[i] = ldf(lw, wofs + i, f);
  if(t < 64) B[t] = ldf(lb, bofs + t, f);
  const int w = t >> 6, lane = t & 63;
  // GraphNorm params of layer-1 (identity for layer 0: encoder out is final)
  float c = 0.f, a = 1.f, bb = 0.f;
  if(layer > 0){
    const int pl = layer - 1;
    const float* __restrict__ st = stats + (size_t)pl*1024;
    const size_t pofs = (size_t)pl*64;
    float s1 = 0.f, s2 = 0.f;
#pragma unroll
    for(int k = 0; k < 8; k++){ s1 += st[k*128 + lane]; s2 += st[k*128 + 64 + lane]; }
    const float mean = s1*invN, ex2 = s2*invN;
    c = mean * ldf(gms, pofs + lane, f);
    const float var = ex2 - 2.f*c*mean + c*c;   // E[(x-c)^2]
    a = ldf(gw, pofs + lane, f) / sqrtf(var + 1e-5f);
    bb = ldf(gb, pofs + lane, f);
  }
  __syncthreads();
  // hoist this lane's W column into registers (64 VGPR, static indices)
  float wreg[64];
#pragma unroll
  for(int k = 0; k < 64; k++) wreg[k] = W[k*64 + lane];
  const float blane = B[lane];
  for(int base = blockIdx.x*4; base < N; base += gridDim.x*4){
    const int node = base + w;
    if(node < N){
      const size_t idx = (size_t)node*64 + lane;
      float v = x[idx];
      if(layer > 0){
        v = lrelu((v - c)*a + bb, 0.01f);
        float hv = 0.5f*v + (layer == 1 ? 0.f : ldf(out, h_base + idx, f));
        stf(out, h_base + idx, f, hv);
      }
      XR[w][lane] = v;   // wave-private row: in-order LDS within wave, no barrier
      float acc = blane;
      const float4* xr4 = (const float4*)XR[w];
#pragma unroll
      for(int k4 = 0; k4 < 16; k4++){
        const float4 xv = xr4[k4];   // broadcast ds_read_b128
        acc = fmaf(xv.x, wreg[4*k4+0], acc);
        acc = fmaf(xv.y, wreg[4*k4+1], acc);
        acc = fmaf(xv.z, wreg[4*k4+2], acc);
        acc = fmaf(xv.w, wreg[4*k4+3], acc);
      }
      g[idx] = acc;
    }
  }
  // alpha of layer-1: CSR order -> original edge order
  if(layer > 0){
    for(size_t j = (size_t)blockIdx.x*256 + threadIdx.x; j < (size_t)T;
        j += (size_t)gridDim.x*256)
      stf(out, alpha_base + j, f, acsr[pos[j]]);
  }
}

// ---- CSR build --------------------------------------------------------------
__global__ void k_deg_init(int* deg, float* stats, int N){
  int i = blockIdx.x*blockDim.x + threadIdx.x;
  if(i < N) deg[i] = 1;
  if(i < 4096) stats[i] = 0.f;
}
__global__ void k_deg_count(const int* __restrict__ dst, int* deg, int E){
  int j = blockIdx.x*blockDim.x + threadIdx.x;
  if(j < E) atomicAdd(&deg[dst[j]], 1);
}
__global__ __launch_bounds__(256) void k_scan_partial(const int* __restrict__ deg, int* partial, int N){
  __shared__ int red[256];
  const int c = blockIdx.x, base = c*1024, t = threadIdx.x;
  int s = 0;
  for(int i = t; i < 1024; i += 256){ int idx = base+i; s += (idx < N) ? deg[idx] : 0; }
  red[t] = s; __syncthreads();
  for(int o = 128; o > 0; o >>= 1){ if(t < o) red[t] += red[t+o]; __syncthreads(); }
  if(t == 0) partial[c] = red[0];
}
// top-level chunk prefix folded in: each block parallel-reduces partial[0..c)
__global__ __launch_bounds__(256) void k_scan_final(
    const int* __restrict__ deg, const int* __restrict__ partial,
    int* __restrict__ off, int* __restrict__ cur, int N, int nchunks)
{
  __shared__ int vals[1024];
  __shared__ int tsum[256];
  __shared__ int red[256];
  const int c = blockIdx.x, base = c*1024, t = threadIdx.x;
  red[t] = (t < c && t < nchunks) ? partial[t] : 0;
  for(int i = t; i < 1024; i += 256){ int idx = base+i; vals[i] = (idx < N) ? deg[idx] : 0; }
  __syncthreads();
  for(int o = 128; o > 0; o >>= 1){ if(t < o) red[t] += red[t+o]; __syncthreads(); }
  const int cbase = red[0];
  int a0 = vals[t*4], a1 = vals[t*4+1], a2 = vals[t*4+2], a3 = vals[t*4+3];
  int s = a0+a1+a2+a3;
  tsum[t] = s; __syncthreads();
  for(int o = 1; o < 256; o <<= 1){
    int v = (t >= o) ? tsum[t-o] : 0;
    __syncthreads();
    tsum[t] += v;
    __syncthreads();
  }
  int excl = tsum[t] - s + cbase;
  int o0 = excl, o1 = o0+a0, o2 = o1+a1, o3 = o2+a2;
  int idx = base + t*4;
  if(idx   < N){ off[idx]   = o0; cur[idx]   = o0; }
  if(idx+1 < N){ off[idx+1] = o1; cur[idx+1] = o1; }
  if(idx+2 < N){ off[idx+2] = o2; cur[idx+2] = o2; }
  if(idx+3 < N){ off[idx+3] = o3; cur[idx+3] = o3; }
}
// single-pass scatter: one scattered 4B write (csrc, NON-TEMPORAL to bypass
// L2 line-thrash: FETCH~0 shows no read-allocate; the 114MB WRITE_SIZE is
// 64B-line writeback amplification. nt hints write-through/smaller bursts),
// one coalesced write (pos).
__global__ void k_scatter(const int* __restrict__ src, const int* __restrict__ dst,
                          int* cur, int* __restrict__ pos, int* __restrict__ csrc,
                          int E, int N){
  int j = blockIdx.x*blockDim.x + threadIdx.x;
  int T = E + N;
  if(j >= T) return;
  int s, d;
  if(j < E){ s = src[j]; d = dst[j]; } else { s = j - E; d = s; }
  int p = atomicAdd(&cur[d], 1);
  __builtin_nontemporal_store(s, &csrc[p]);   // scattered (unavoidable), NT
  pos[j]  = p;                                 // coalesced
}

// ---- fused GATv2: GRID-STRIDED (2048 blocks), quarter-wave, 2 independent
//      online-softmax chains per quarter (8 edges in flight), depth-2
//      pipelined gather (fp32 g). Stats accumulated in REGISTERS across
//      node-groups, one atomic flush per lane at kernel end (atomics/layer
//      3.2M -> ~0.26M; prologue amortized ~12x; sv/sv2 LDS + barriers gone).
__global__ __launch_bounds__(256) void k_gat(
    const float* __restrict__ g, const int* __restrict__ off,
    const int* __restrict__ deg, const int* __restrict__ csrc,
    const void* __restrict__ att, const void* __restrict__ convb,
    float* __restrict__ xout, float* __restrict__ acsr,
    float* __restrict__ stats, const int* __restrict__ flagp,
    int layer, int N)
{
  const int t = threadIdx.x, w = t >> 6, lane = t & 63;
  const int q = lane >> 4, L = lane & 15;
  const int f = *flagp;
  const size_t pofs = (size_t)layer*64;
  float* __restrict__ st = stats + (size_t)layer*1024;

  // per-lane channel block c = 4L..4L+3 (same in every quarter)
  float4 attv, cbv;
  attv.x = ldf(att, pofs + 4*L+0, f); attv.y = ldf(att, pofs + 4*L+1, f);
  attv.z = ldf(att, pofs + 4*L+2, f); attv.w = ldf(att, pofs + 4*L+3, f);
  cbv.x = ldf(convb, pofs + 4*L+0, f); cbv.y = ldf(convb, pofs + 4*L+1, f);
  cbv.z = ldf(convb, pofs + 4*L+2, f); cbv.w = ldf(convb, pofs + 4*L+3, f);

  float s1a[4] = {0.f,0.f,0.f,0.f};   // stats partials (q==0 lanes)
  float s2a[4] = {0.f,0.f,0.f,0.f};

  const int ngrp = (N + 3) >> 2;
  for(int grp = blockIdx.x; grp < ngrp; grp += gridDim.x){
    const int node = grp*4 + w;
    const bool act = node < N;
    const int nc = act ? node : (N-1);

    const float4 gd = *(const float4*)(g + (size_t)nc*64 + 4*L);
    const int o = off[nc];
    const int d = act ? deg[nc] : 0;
    // preload up to 64 source ids, coalesced; broadcast later via shfl
    const int sreg = csrc[o + (lane < d ? lane : 0)];

    // iteration i covers edges j = 8i + 2q + {0,1}; main loop covers j < 64.
    const int nitm = min((d + 7) >> 3, 8);

    float m0 = -1e30f, sp0 = 0.f, m1 = -1e30f, sp1 = 0.f, ereg = -1e30f;
    float4 ac0 = {0.f,0.f,0.f,0.f}, ac1 = {0.f,0.f,0.f,0.f};

    // depth-2 pipeline over iterations, 2 rows per iteration
    float4 rA0 = {0.f,0.f,0.f,0.f}, rA1 = rA0, rB0 = rA0, rB1 = rA0;
    {
      const int s00 = __shfl(sreg, 2*q,   64);
      const int s01 = __shfl(sreg, 2*q+1, 64);
      rA0 = *(const float4*)(g + (size_t)s00*64 + 4*L);
      rA1 = *(const float4*)(g + (size_t)s01*64 + 4*L);
    }
    if(nitm > 1){
      const int s10 = __shfl(sreg, 8+2*q,   64);
      const int s11 = __shfl(sreg, 8+2*q+1, 64);
      rB0 = *(const float4*)(g + (size_t)s10*64 + 4*L);
      rB1 = *(const float4*)(g + (size_t)s11*64 + 4*L);
    }
    for(int i = 0; i < nitm; i++){
      float4 n0 = {0.f,0.f,0.f,0.f}, n1 = {0.f,0.f,0.f,0.f};
      const bool more = (i + 2) < nitm;
      if(more){
        const int t0 = __shfl(sreg, 8*(i+2)+2*q,   64);   // index <= 63
        const int t1 = __shfl(sreg, 8*(i+2)+2*q+1, 64);
        n0 = *(const float4*)(g + (size_t)t0*64 + 4*L);
        n1 = *(const float4*)(g + (size_t)t1*64 + 4*L);
      }
      const int j0 = 8*i + 2*q;
      float pe0 = lrelu(rA0.x+gd.x, 0.2f)*attv.x + lrelu(rA0.y+gd.y, 0.2f)*attv.y
                + lrelu(rA0.z+gd.z, 0.2f)*attv.z + lrelu(rA0.w+gd.w, 0.2f)*attv.w;
      float pe1 = lrelu(rA1.x+gd.x, 0.2f)*attv.x + lrelu(rA1.y+gd.y, 0.2f)*attv.y
                + lrelu(rA1.z+gd.z, 0.2f)*attv.z + lrelu(rA1.w+gd.w, 0.2f)*attv.w;
      float e0 = qsum(pe0);
      float e1 = qsum(pe1);
      if(j0   >= d) e0 = -1e30f;
      if(j0+1 >= d) e1 = -1e30f;
      // lane (q,L) caches e of edge 8*(L>>1)+2q+(L&1)
      ereg = (L == 2*i  ) ? e0 : ereg;
      ereg = (L == 2*i+1) ? e1 : ereg;
      { const float mn = fmaxf(m0, e0);
        const float sc = __expf(m0 - mn), wt = __expf(e0 - mn);
        sp0   = sp0*sc   + wt;
        ac0.x = ac0.x*sc + wt*rA0.x; ac0.y = ac0.y*sc + wt*rA0.y;
        ac0.z = ac0.z*sc + wt*rA0.z; ac0.w = ac0.w*sc + wt*rA0.w;
        m0 = mn; }
      { const float mn = fmaxf(m1, e1);
        const float sc = __expf(m1 - mn), wt = __expf(e1 - mn);
        sp1   = sp1*sc   + wt;
        ac1.x = ac1.x*sc + wt*rA1.x; ac1.y = ac1.y*sc + wt*rA1.y;
        ac1.z = ac1.z*sc + wt*rA1.z; ac1.w = ac1.w*sc + wt*rA1.w;
        m1 = mn; }
      rA0 = rB0; rA1 = rB1;
      if(more){ rB0 = n0; rB1 = n1; }
    }
    // merge chain1 into chain0 (register-local)
    float m = fmaxf(m0, m1), sp;
    float4 acc;
    {
      const float sA = __expf(m0 - m), sB = __expf(m1 - m);
      sp    = sp0*sA   + sp1*sB;
      acc.x = ac0.x*sA + ac1.x*sB; acc.y = ac0.y*sA + ac1.y*sB;
      acc.z = ac0.z*sA + ac1.z*sB; acc.w = ac0.w*sA + ac1.w*sB;
    }
    // merge the 4 per-quarter states (xor 16, then 32)
#pragma unroll
    for(int ofs = 16; ofs <= 32; ofs <<= 1){
      const float m2  = __shfl_xor(m,  ofs, 64);
      const float sp2 = __shfl_xor(sp, ofs, 64);
      float4 a2;
      a2.x = __shfl_xor(acc.x, ofs, 64); a2.y = __shfl_xor(acc.y, ofs, 64);
      a2.z = __shfl_xor(acc.z, ofs, 64); a2.w = __shfl_xor(acc.w, ofs, 64);
      const float mn = fmaxf(m, m2);
      const float sA = __expf(m - mn), sB = __expf(m2 - mn);
      sp    = sp*sA    + sp2*sB;
      acc.x = acc.x*sA + a2.x*sB;
      acc.y = acc.y*sA + a2.y*sB;
      acc.z = acc.z*sA + a2.z*sB;
      acc.w = acc.w*sA + a2.w*sB;
      m = mn;
    }
    const float inv = 1.f / sp;

    if(act){
      // alpha for edges < min(d,64): lane (q,L) holds e of edge 4(L&~1)+2q+(L&1)
      const int jc = 4*(L & ~1) + 2*q + (L & 1);
      if(jc < d && jc < 64)
        acsr[o + jc] = __expf(ereg - m) * inv;
      // rare tail d>64: recompute e (one edge per quarter per step)
      for(int j2 = 64 + q; j2 < d; j2 += 4){
        const int s = csrc[o + j2];
        const float4 gs2 = *(const float4*)(g + (size_t)s*64 + 4*L);
        float pe = lrelu(gs2.x+gd.x, 0.2f)*attv.x + lrelu(gs2.y+gd.y, 0.2f)*attv.y
                 + lrelu(gs2.z+gd.z, 0.2f)*attv.z + lrelu(gs2.w+gd.w, 0.2f)*attv.w;
        float e = qsum(pe);
        if(L == 0)
          acsr[o + j2] = __expf(e - m) * inv;
      }
      if(q == 0){
        float4 v4;
        v4.x = acc.x*inv + cbv.x; v4.y = acc.y*inv + cbv.y;
        v4.z = acc.z*inv + cbv.z; v4.w = acc.w*inv + cbv.w;
        *(float4*)(xout + (size_t)node*64 + 4*L) = v4;
        s1a[0] += v4.x;      s1a[1] += v4.y;
        s1a[2] += v4.z;      s1a[3] += v4.w;
        s2a[0] += v4.x*v4.x; s2a[1] += v4.y*v4.y;
        s2a[2] += v4.z*v4.z; s2a[3] += v4.w*v4.w;
      }
    }
  }
  // one flush per q==0 lane (8 atomics), 8-bank spread by block
  if(q == 0){
    const int bank = (blockIdx.x & 7) * 128;
    atomicAdd(&st[bank + 4*L+0],      s1a[0]);
    atomicAdd(&st[bank + 4*L+1],      s1a[1]);
    atomicAdd(&st[bank + 4*L+2],      s1a[2]);
    atomicAdd(&st[bank + 4*L+3],      s1a[3]);
    atomicAdd(&st[bank + 64 + 4*L+0], s2a[0]);
    atomicAdd(&st[bank + 64 + 4*L+1], s2a[1]);
    atomicAdd(&st[bank + 64 + 4*L+2], s2a[2]);
    atomicAdd(&st[bank + 64 + 4*L+3], s2a[3]);
  }
}

// ---- final GraphNorm (layer 3 only) + output emission -----------------------
__global__ __launch_bounds__(256) void k_gn_final(
    const float* __restrict__ x, const float* __restrict__ stats,
    const void* __restrict__ gw, const void* __restrict__ gb,
    const void* __restrict__ gms, void* __restrict__ out,
    const float* __restrict__ acsr, const int* __restrict__ pos,
    size_t x_base, size_t h_base, size_t alpha_base,
    const int* __restrict__ flagp, int N, int T, float invN)
{
  const int f = *flagp;
  const int lane = threadIdx.x & 63;
  const float* __restrict__ st = stats + (size_t)3*1024;
  const size_t pofs = (size_t)3*64;
  float s1 = 0.f, s2 = 0.f;
#pragma unroll
  for(int c = 0; c < 8; c++){
    s1 += st[c*128 + lane];
    s2 += st[c*128 + 64 + lane];
  }
  const float mean = s1 * invN;
  const float ex2  = s2 * invN;
  const float c    = mean * ldf(gms, pofs + lane, f);
  const float var  = ex2 - 2.f*c*mean + c*c;   // E[(x-c)^2]
  const float a    = ldf(gw, pofs + lane, f) / sqrtf(var + 1e-5f);
  const float bb   = ldf(gb, pofs + lane, f);
  const size_t total = (size_t)N * 64;
  for(size_t idx = (size_t)blockIdx.x*256 + threadIdx.x; idx < total;
      idx += (size_t)gridDim.x*256){
    float v = (x[idx] - c) * a + bb;
    v = lrelu(v, 0.01f);
    float hv = 0.5f*v + ldf(out, h_base + idx, f);
    stf(out, h_base + idx, f, hv);
    stf(out, x_base + idx, f, v);
  }
  for(size_t j = (size_t)blockIdx.x*256 + threadIdx.x; j < (size_t)T;
      j += (size_t)gridDim.x*256){
    stf(out, alpha_base + j, f, acsr[pos[j]]);
  }
}

// ---- host launch ------------------------------------------------------------
extern "C" void kernel_launch(void* const* d_in, const int* in_sizes, int n_in,
                              void* d_out, int out_size, void* d_ws, size_t ws_size,
                              hipStream_t stream) {
  const void* xf   = d_in[0];
  const int*  ids  = (const int*)d_in[1];
  const int*  eidx = (const int*)d_in[2];
  const void* emb  = d_in[3];
  const void* win  = d_in[4];
  const void* bin  = d_in[5];
  const void* lw   = d_in[6];
  const void* lb   = d_in[7];
  const void* att  = d_in[8];
  const void* cb   = d_in[9];
  const void* gw   = d_in[10];
  const void* gb   = d_in[11];
  const void* gms  = d_in[12];

  const int N = in_sizes[1];
  const int E = in_sizes[2] / 2;
  const int T = E + N;
  const int* srcp = eidx;
  const int* dstp = eidx + E;

  // workspace carve (~74 MB)
  char* p = (char*)d_ws;
  float* x  = (float*)p; p += (size_t)N*64*4;
  float* g  = (float*)p; p += (size_t)N*64*4;
  int* deg  = (int*)p;   p += ((size_t)N*4 + 63) & ~63ull;
  int* off  = (int*)p;   p += ((size_t)N*4 + 63) & ~63ull;
  int* cur  = (int*)p;   p += ((size_t)N*4 + 63) & ~63ull;
  int* pos  = (int*)p;   p += ((size_t)T*4 + 63) & ~63ull;
  int* csrc = (int*)p;   p += ((size_t)T*4 + 63) & ~63ull;
  float* acsr = (float*)p; p += ((size_t)T*4 + 63) & ~63ull;
  int* partial = (int*)p; p += 4096;
  float* stats = (float*)p; p += 4*1024*4;   // 4 layers x 8 banks x 128 floats
  int* flag = (int*)p;   p += 64;

  const size_t x_base = 0;
  const size_t h_base = (size_t)N*64;
  const size_t a_base = (size_t)2*N*64;
  const float invN = 1.0f/(float)N;

  k_detect<<<1, 64, 0, stream>>>((const uint32_t*)xf, flag);
  k_encoder<<<2048, 256, 0, stream>>>(xf, ids, emb, win, bin, x, flag, N);

  k_deg_init <<<(N+255)/256, 256, 0, stream>>>(deg, stats, N);
  k_deg_count<<<(E+255)/256, 256, 0, stream>>>(dstp, deg, E);
  const int nchunks = (N + 1023) / 1024;
  k_scan_partial<<<nchunks, 256, 0, stream>>>(deg, partial, N);
  k_scan_final  <<<nchunks, 256, 0, stream>>>(deg, partial, off, cur, N, nchunks);
  k_scatter     <<<(T+255)/256, 256, 0, stream>>>(srcp, dstp, cur, pos, csrc, E, N);

  for(int l = 0; l < 4; l++){
    // linear of layer l; also applies GN of layer l-1 and emits its h/alpha
    k_linear<<<2048, 256, 0, stream>>>(x, lw, lb, g, stats, gw, gb, gms,
                                       d_out, acsr, pos, h_base,
                                       a_base + (size_t)(l-1)*T,
                                       flag, l, N, T, invN);
    k_gat<<<2048, 256, 0, stream>>>(g, off, deg, csrc, att, cb, x,
                                    acsr, stats, flag, l, N);
  }
  k_gn_final<<<1024, 256, 0, stream>>>(x, stats, gw, gb, gms, d_out,
                                       acsr, pos, x_base, h_base,
                                       a_base + (size_t)3*T, flag, N, T, invN);
}

// Round 10
// 1032.909 us; speedup vs baseline: 1.2832x; 1.2832x over previous
//
#include <hip/hip_runtime.h>
#include <hip/hip_bf16.h>
#include <cstdint>

typedef __hip_bfloat16 bf16;
#define DEVI __device__ __forceinline__

DEVI float b2f(bf16 v){ return __bfloat162float(v); }
DEVI bf16 f2b(float v){ return __float2bfloat16(v); }
DEVI float lrelu(float x, float s){ return x > 0.f ? x : x * s; }

// dtype-adaptive accessors: f==1 -> bf16 data, f==0 -> float32 data
DEVI float ldf(const void* p, size_t i, int f){
  return f ? b2f(((const bf16*)p)[i]) : ((const float*)p)[i];
}
DEVI void stf(void* p, size_t i, int f, float v){
  if(f) ((bf16*)p)[i] = f2b(v); else ((float*)p)[i] = v;
}

DEVI float wave_sum(float v){
#pragma unroll
  for(int o = 32; o > 0; o >>= 1) v += __shfl_xor(v, o, 64);
  return v;
}
// sum within 16-lane quarter (4 quarters reduce simultaneously)
DEVI float qsum(float v){
  v += __shfl_xor(v, 1, 64);
  v += __shfl_xor(v, 2, 64);
  v += __shfl_xor(v, 4, 64);
  v += __shfl_xor(v, 8, 64);
  return v;
}

// ---- dtype detector ---------------------------------------------------------
__global__ void k_detect(const uint32_t* __restrict__ xf, int* flag){
  const int lane = threadIdx.x & 63;
  float cnt = 0.f;
  for(int i = lane; i < 256; i += 64){
    uint32_t e = (xf[i] >> 7) & 0xFF;
    if(e >= 100 && e <= 140) cnt += 1.f;
  }
  cnt = wave_sum(cnt);
  if(lane == 0 && blockIdx.x == 0) *flag = (cnt > 180.f) ? 1 : 0;
}

// ---- param pre-convert: att/conv_b/gn_w/gn_b/gn_ms -> fp32 [5][4][64] -------
// Removes per-block branchy dtype-adaptive loads from hot kernels.
__global__ void k_params(const void* __restrict__ att, const void* __restrict__ cb,
                         const void* __restrict__ gw, const void* __restrict__ gb,
                         const void* __restrict__ gms, const int* __restrict__ flagp,
                         float* __restrict__ pf){
  const int f = *flagp;
  for(int k = threadIdx.x; k < 1280; k += 256){
    const int arr = k >> 8, ofs = k & 255;  // 256 = 4 layers x 64
    const void* src = arr==0?att : arr==1?cb : arr==2?gw : arr==3?gb : gms;
    pf[k] = ldf(src, ofs, f);
  }
}

// ---- encoder ----------------------------------------------------------------
__global__ __launch_bounds__(256) void k_encoder(
    const void* __restrict__ xf, const int* __restrict__ ids,
    const void* __restrict__ emb, const void* __restrict__ win,
    const void* __restrict__ bin, float* __restrict__ x,
    const int* __restrict__ flagp, int N)
{
  __shared__ float W[128*64];
  __shared__ float B[64];
  __shared__ float XR[4][128];
  const int t = threadIdx.x;
  const int f = *flagp;
  for(int i = t; i < 128*64; i += 256) W[i] = ldf(win, i, f);
  if(t < 64) B[t] = ldf(bin, t, f);
  __syncthreads();
  const int w = t >> 6, lane = t & 63;
  for(int base = blockIdx.x*4; base < N; base += gridDim.x*4){
    const int node = base + w;
    if(node < N){
      for(int k = lane; k < 128; k += 64){
        float v;
        if(k < 124) v = ldf(xf, (size_t)node*124 + k, f);
        else        v = ldf(emb, (size_t)ids[node]*4 + (k-124), f);
        XR[w][k] = v;
      }
      float acc = B[lane];
#pragma unroll 8
      for(int k = 0; k < 128; k++) acc = fmaf(XR[w][k], W[k*64+lane], acc);
      x[(size_t)node*64 + lane] = lrelu(acc, 0.01f);
    }
  }
}

// ---- per-layer linear, with layer-(l-1) GraphNorm fused in -----------------
// W column held in 64 VGPRs (hoisted once); XR read via broadcast float4.
__global__ __launch_bounds__(256) void k_linear(
    const float* __restrict__ x, const void* __restrict__ lw,
    const void* __restrict__ lb, float* __restrict__ g,
    const float* __restrict__ stats, const float* __restrict__ pf,
    void* __restrict__ out, const float* __restrict__ acsr,
    const int* __restrict__ pos, size_t h_base, size_t alpha_base,
    const int* __restrict__ flagp, int layer, int N, int T, float invN)
{
  __shared__ float W[64*64];
  __shared__ float B[64];
  __shared__ float XR[4][64];
  const int t = threadIdx.x;
  const int f = *flagp;
  const size_t wofs = (size_t)layer*64*64, bofs = (size_t)layer*64;
  for(int i = t; i < 64*64; i += 256) W[i] = ldf(lw, wofs + i, f);
  if(t < 64) B[t] = ldf(lb, bofs + t, f);
  const int w = t >> 6, lane = t & 63;
  // GraphNorm params of layer-1 (identity for layer 0: encoder out is final)
  float c = 0.f, a = 1.f, bb = 0.f;
  if(layer > 0){
    const int pl = layer - 1;
    const float* __restrict__ st = stats + (size_t)pl*1024;
    const int pofs = pl*64 + lane;
    float s1 = 0.f, s2 = 0.f;
#pragma unroll
    for(int k = 0; k < 8; k++){ s1 += st[k*128 + lane]; s2 += st[k*128 + 64 + lane]; }
    const float mean = s1*invN, ex2 = s2*invN;
    c = mean * pf[4*256 + pofs];                    // gn_ms
    const float var = ex2 - 2.f*c*mean + c*c;       // E[(x-c)^2]
    a = pf[2*256 + pofs] / sqrtf(var + 1e-5f);      // gn_w
    bb = pf[3*256 + pofs];                          // gn_b
  }
  __syncthreads();
  // hoist this lane's W column into registers (64 VGPR, static indices)
  float wreg[64];
#pragma unroll
  for(int k = 0; k < 64; k++) wreg[k] = W[k*64 + lane];
  const float blane = B[lane];
  for(int base = blockIdx.x*4; base < N; base += gridDim.x*4){
    const int node = base + w;
    if(node < N){
      const size_t idx = (size_t)node*64 + lane;
      float v = x[idx];
      if(layer > 0){
        v = lrelu((v - c)*a + bb, 0.01f);
        float hv = 0.5f*v + (layer == 1 ? 0.f : ldf(out, h_base + idx, f));
        stf(out, h_base + idx, f, hv);
      }
      XR[w][lane] = v;   // wave-private row: in-order LDS within wave, no barrier
      float acc = blane;
      const float4* xr4 = (const float4*)XR[w];
#pragma unroll
      for(int k4 = 0; k4 < 16; k4++){
        const float4 xv = xr4[k4];   // broadcast ds_read_b128
        acc = fmaf(xv.x, wreg[4*k4+0], acc);
        acc = fmaf(xv.y, wreg[4*k4+1], acc);
        acc = fmaf(xv.z, wreg[4*k4+2], acc);
        acc = fmaf(xv.w, wreg[4*k4+3], acc);
      }
      g[idx] = acc;
    }
  }
  // alpha of layer-1: CSR order -> original edge order
  if(layer > 0){
    for(size_t j = (size_t)blockIdx.x*256 + threadIdx.x; j < (size_t)T;
        j += (size_t)gridDim.x*256)
      stf(out, alpha_base + j, f, acsr[pos[j]]);
  }
}

// ---- CSR build --------------------------------------------------------------
__global__ void k_deg_init(int* deg, float* stats, int N){
  int i = blockIdx.x*blockDim.x + threadIdx.x;
  if(i < N) deg[i] = 1;
  if(i < 4096) stats[i] = 0.f;
}
__global__ void k_deg_count(const int* __restrict__ dst, int* deg, int E){
  int j = blockIdx.x*blockDim.x + threadIdx.x;
  if(j < E) atomicAdd(&deg[dst[j]], 1);
}
__global__ __launch_bounds__(256) void k_scan_partial(const int* __restrict__ deg, int* partial, int N){
  __shared__ int red[256];
  const int c = blockIdx.x, base = c*1024, t = threadIdx.x;
  int s = 0;
  for(int i = t; i < 1024; i += 256){ int idx = base+i; s += (idx < N) ? deg[idx] : 0; }
  red[t] = s; __syncthreads();
  for(int o = 128; o > 0; o >>= 1){ if(t < o) red[t] += red[t+o]; __syncthreads(); }
  if(t == 0) partial[c] = red[0];
}
// top-level chunk prefix folded in: each block parallel-reduces partial[0..c)
__global__ __launch_bounds__(256) void k_scan_final(
    const int* __restrict__ deg, const int* __restrict__ partial,
    int* __restrict__ off, int* __restrict__ cur, int N, int nchunks)
{
  __shared__ int vals[1024];
  __shared__ int tsum[256];
  __shared__ int red[256];
  const int c = blockIdx.x, base = c*1024, t = threadIdx.x;
  red[t] = (t < c && t < nchunks) ? partial[t] : 0;
  for(int i = t; i < 1024; i += 256){ int idx = base+i; vals[i] = (idx < N) ? deg[idx] : 0; }
  __syncthreads();
  for(int o = 128; o > 0; o >>= 1){ if(t < o) red[t] += red[t+o]; __syncthreads(); }
  const int cbase = red[0];
  int a0 = vals[t*4], a1 = vals[t*4+1], a2 = vals[t*4+2], a3 = vals[t*4+3];
  int s = a0+a1+a2+a3;
  tsum[t] = s; __syncthreads();
  for(int o = 1; o < 256; o <<= 1){
    int v = (t >= o) ? tsum[t-o] : 0;
    __syncthreads();
    tsum[t] += v;
    __syncthreads();
  }
  int excl = tsum[t] - s + cbase;
  int o0 = excl, o1 = o0+a0, o2 = o1+a1, o3 = o2+a2;
  int idx = base + t*4;
  if(idx   < N){ off[idx]   = o0; cur[idx]   = o0; }
  if(idx+1 < N){ off[idx+1] = o1; cur[idx+1] = o1; }
  if(idx+2 < N){ off[idx+2] = o2; cur[idx+2] = o2; }
  if(idx+3 < N){ off[idx+3] = o3; cur[idx+3] = o3; }
}
// single-pass scatter: one scattered 4B NT write (csrc), one coalesced (pos).
// The scattered write materializes the inverse permutation ONCE; all 4 layers
// then pay only cache-resident scattered READS (acsr[pos[j]]).
__global__ void k_scatter(const int* __restrict__ src, const int* __restrict__ dst,
                          int* cur, int* __restrict__ pos, int* __restrict__ csrc,
                          int E, int N){
  int j = blockIdx.x*blockDim.x + threadIdx.x;
  int T = E + N;
  if(j >= T) return;
  int s, d;
  if(j < E){ s = src[j]; d = dst[j]; } else { s = j - E; d = s; }
  int p = atomicAdd(&cur[d], 1);
  __builtin_nontemporal_store(s, &csrc[p]);   // scattered (unavoidable), NT
  pos[j]  = p;                                 // coalesced
}

// ---- fused GATv2: per-node blocks (block-churn overlaps prologue/epilogue
//      across blocks — grid-stride variant measured +36us/layer, reverted).
//      Quarter-wave, 2 online-softmax chains/quarter (8 edges in flight),
//      depth-2 pipelined gather (fp32 g). Params from fp32 pf buffer.
__global__ __launch_bounds__(256) void k_gat(
    const float* __restrict__ g, const int* __restrict__ off,
    const int* __restrict__ deg, const int* __restrict__ csrc,
    const float* __restrict__ pf, float* __restrict__ xout,
    float* __restrict__ acsr, float* __restrict__ stats,
    int layer, int N)
{
  __shared__ float sv[4][64], sv2[4][64];
  const int t = threadIdx.x, w = t >> 6, lane = t & 63;
  const int q = lane >> 4, L = lane & 15;
  float* __restrict__ st = stats + (size_t)layer*1024;
  const int node = blockIdx.x*4 + w;
  const bool act = node < N;
  const int nc = act ? node : (N-1);

  // per-lane channel block c = 4L..4L+3 (same in every quarter); fp32 params
  const float4 attv = *(const float4*)(pf +       layer*64 + 4*L);
  const float4 cbv  = *(const float4*)(pf + 256 + layer*64 + 4*L);

  const float4 gd = *(const float4*)(g + (size_t)nc*64 + 4*L);
  const int o = off[nc];
  const int d = act ? deg[nc] : 0;
  // preload up to 64 source ids, coalesced; broadcast later via shfl
  const int sreg = csrc[o + (lane < d ? lane : 0)];

  // iteration i covers edges j = 8i + 2q + {0,1}; main loop covers j < 64.
  const int nitm = min((d + 7) >> 3, 8);

  float m0 = -1e30f, sp0 = 0.f, m1 = -1e30f, sp1 = 0.f, ereg = -1e30f;
  float4 ac0 = {0.f,0.f,0.f,0.f}, ac1 = {0.f,0.f,0.f,0.f};

  // ---- depth-2 pipeline over iterations, 2 rows per iteration --------------
  float4 rA0 = {0.f,0.f,0.f,0.f}, rA1 = rA0, rB0 = rA0, rB1 = rA0;
  {
    const int s00 = __shfl(sreg, 2*q,   64);
    const int s01 = __shfl(sreg, 2*q+1, 64);
    rA0 = *(const float4*)(g + (size_t)s00*64 + 4*L);
    rA1 = *(const float4*)(g + (size_t)s01*64 + 4*L);
  }
  if(nitm > 1){
    const int s10 = __shfl(sreg, 8+2*q,   64);
    const int s11 = __shfl(sreg, 8+2*q+1, 64);
    rB0 = *(const float4*)(g + (size_t)s10*64 + 4*L);
    rB1 = *(const float4*)(g + (size_t)s11*64 + 4*L);
  }
  for(int i = 0; i < nitm; i++){
    // prefetch iteration i+2's rows (independent of current consume)
    float4 n0 = {0.f,0.f,0.f,0.f}, n1 = {0.f,0.f,0.f,0.f};
    const bool more = (i + 2) < nitm;
    if(more){
      const int t0 = __shfl(sreg, 8*(i+2)+2*q,   64);   // index <= 63
      const int t1 = __shfl(sreg, 8*(i+2)+2*q+1, 64);
      n0 = *(const float4*)(g + (size_t)t0*64 + 4*L);
      n1 = *(const float4*)(g + (size_t)t1*64 + 4*L);
    }
    // consume edges j0 = 8i+2q (chain0) and j0+1 (chain1)
    const int j0 = 8*i + 2*q;
    float pe0 = lrelu(rA0.x+gd.x, 0.2f)*attv.x + lrelu(rA0.y+gd.y, 0.2f)*attv.y
              + lrelu(rA0.z+gd.z, 0.2f)*attv.z + lrelu(rA0.w+gd.w, 0.2f)*attv.w;
    float pe1 = lrelu(rA1.x+gd.x, 0.2f)*attv.x + lrelu(rA1.y+gd.y, 0.2f)*attv.y
              + lrelu(rA1.z+gd.z, 0.2f)*attv.z + lrelu(rA1.w+gd.w, 0.2f)*attv.w;
    float e0 = qsum(pe0);
    float e1 = qsum(pe1);
    if(j0   >= d) e0 = -1e30f;
    if(j0+1 >= d) e1 = -1e30f;
    // lane (q,L) caches e of edge 8*(L>>1)+2q+(L&1)
    ereg = (L == 2*i  ) ? e0 : ereg;
    ereg = (L == 2*i+1) ? e1 : ereg;
    { const float mn = fmaxf(m0, e0);
      const float sc = __expf(m0 - mn), wt = __expf(e0 - mn);
      sp0   = sp0*sc   + wt;
      ac0.x = ac0.x*sc + wt*rA0.x; ac0.y = ac0.y*sc + wt*rA0.y;
      ac0.z = ac0.z*sc + wt*rA0.z; ac0.w = ac0.w*sc + wt*rA0.w;
      m0 = mn; }
    { const float mn = fmaxf(m1, e1);
      const float sc = __expf(m1 - mn), wt = __expf(e1 - mn);
      sp1   = sp1*sc   + wt;
      ac1.x = ac1.x*sc + wt*rA1.x; ac1.y = ac1.y*sc + wt*rA1.y;
      ac1.z = ac1.z*sc + wt*rA1.z; ac1.w = ac1.w*sc + wt*rA1.w;
      m1 = mn; }
    rA0 = rB0; rA1 = rB1;
    if(more){ rB0 = n0; rB1 = n1; }
  }
  // merge chain1 into chain0 (register-local)
  float m = fmaxf(m0, m1), sp;
  float4 acc;
  {
    const float sA = __expf(m0 - m), sB = __expf(m1 - m);
    sp    = sp0*sA   + sp1*sB;
    acc.x = ac0.x*sA + ac1.x*sB; acc.y = ac0.y*sA + ac1.y*sB;
    acc.z = ac0.z*sA + ac1.z*sB; acc.w = ac0.w*sA + ac1.w*sB;
  }
  // merge the 4 per-quarter states (xor 16, then 32)
#pragma unroll
  for(int ofs = 16; ofs <= 32; ofs <<= 1){
    const float m2  = __shfl_xor(m,  ofs, 64);
    const float sp2 = __shfl_xor(sp, ofs, 64);
    float4 a2;
    a2.x = __shfl_xor(acc.x, ofs, 64); a2.y = __shfl_xor(acc.y, ofs, 64);
    a2.z = __shfl_xor(acc.z, ofs, 64); a2.w = __shfl_xor(acc.w, ofs, 64);
    const float mn = fmaxf(m, m2);
    const float sA = __expf(m - mn), sB = __expf(m2 - mn);
    sp    = sp*sA    + sp2*sB;
    acc.x = acc.x*sA + a2.x*sB;
    acc.y = acc.y*sA + a2.y*sB;
    acc.z = acc.z*sA + a2.z*sB;
    acc.w = acc.w*sA + a2.w*sB;
    m = mn;
  }
  const float inv = 1.f / sp;

  if(act){
    // alpha for edges < min(d,64): lane (q,L) holds e of edge 4(L&~1)+2q+(L&1)
    // (bijection lanes <-> j<64). CSR-ordered write -> fully coalesced span.
    const int jc = 4*(L & ~1) + 2*q + (L & 1);
    if(jc < d && jc < 64)
      acsr[o + jc] = __expf(ereg - m) * inv;
    // rare tail d>64: recompute e (one edge per quarter per step)
    for(int j2 = 64 + q; j2 < d; j2 += 4){
      const int s = csrc[o + j2];
      const float4 gs2 = *(const float4*)(g + (size_t)s*64 + 4*L);
      float pe = lrelu(gs2.x+gd.x, 0.2f)*attv.x + lrelu(gs2.y+gd.y, 0.2f)*attv.y
               + lrelu(gs2.z+gd.z, 0.2f)*attv.z + lrelu(gs2.w+gd.w, 0.2f)*attv.w;
      float e = qsum(pe);
      if(L == 0)
        acsr[o + j2] = __expf(e - m) * inv;
    }
  }
  float4 v4 = {0.f, 0.f, 0.f, 0.f};
  if(act){
    v4.x = acc.x*inv + cbv.x; v4.y = acc.y*inv + cbv.y;
    v4.z = acc.z*inv + cbv.z; v4.w = acc.w*inv + cbv.w;
    if(q == 0) *(float4*)(xout + (size_t)node*64 + 4*L) = v4;
  }
  if(q == 0){
    sv [w][4*L+0] = v4.x;      sv [w][4*L+1] = v4.y;
    sv [w][4*L+2] = v4.z;      sv [w][4*L+3] = v4.w;
    sv2[w][4*L+0] = v4.x*v4.x; sv2[w][4*L+1] = v4.y*v4.y;
    sv2[w][4*L+2] = v4.z*v4.z; sv2[w][4*L+3] = v4.w*v4.w;
  }
  __syncthreads();
  if(w == 0){
    float a = sv[0][lane]+sv[1][lane]+sv[2][lane]+sv[3][lane];
    float b = sv2[0][lane]+sv2[1][lane]+sv2[2][lane]+sv2[3][lane];
    const int bank = (blockIdx.x & 7) * 128;     // spread contention 8x
    atomicAdd(&st[bank + lane],      a);
    atomicAdd(&st[bank + 64 + lane], b);
  }
}

// ---- final GraphNorm (layer 3 only) + output emission -----------------------
__global__ __launch_bounds__(256) void k_gn_final(
    const float* __restrict__ x, const float* __restrict__ stats,
    const float* __restrict__ pf, void* __restrict__ out,
    const float* __restrict__ acsr, const int* __restrict__ pos,
    size_t x_base, size_t h_base, size_t alpha_base,
    const int* __restrict__ flagp, int N, int T, float invN)
{
  const int f = *flagp;
  const int lane = threadIdx.x & 63;
  const float* __restrict__ st = stats + (size_t)3*1024;
  const int pofs = 3*64 + lane;
  float s1 = 0.f, s2 = 0.f;
#pragma unroll
  for(int c = 0; c < 8; c++){
    s1 += st[c*128 + lane];
    s2 += st[c*128 + 64 + lane];
  }
  const float mean = s1 * invN;
  const float ex2  = s2 * invN;
  const float c    = mean * pf[4*256 + pofs];       // gn_ms
  const float var  = ex2 - 2.f*c*mean + c*c;        // E[(x-c)^2]
  const float a    = pf[2*256 + pofs] / sqrtf(var + 1e-5f);  // gn_w
  const float bb   = pf[3*256 + pofs];              // gn_b
  const size_t total = (size_t)N * 64;
  for(size_t idx = (size_t)blockIdx.x*256 + threadIdx.x; idx < total;
      idx += (size_t)gridDim.x*256){
    float v = (x[idx] - c) * a + bb;
    v = lrelu(v, 0.01f);
    float hv = 0.5f*v + ldf(out, h_base + idx, f);
    stf(out, h_base + idx, f, hv);
    stf(out, x_base + idx, f, v);
  }
  for(size_t j = (size_t)blockIdx.x*256 + threadIdx.x; j < (size_t)T;
      j += (size_t)gridDim.x*256){
    stf(out, alpha_base + j, f, acsr[pos[j]]);
  }
}

// ---- host launch ------------------------------------------------------------
extern "C" void kernel_launch(void* const* d_in, const int* in_sizes, int n_in,
                              void* d_out, int out_size, void* d_ws, size_t ws_size,
                              hipStream_t stream) {
  const void* xf   = d_in[0];
  const int*  ids  = (const int*)d_in[1];
  const int*  eidx = (const int*)d_in[2];
  const void* emb  = d_in[3];
  const void* win  = d_in[4];
  const void* bin  = d_in[5];
  const void* lw   = d_in[6];
  const void* lb   = d_in[7];
  const void* att  = d_in[8];
  const void* cb   = d_in[9];
  const void* gw   = d_in[10];
  const void* gb   = d_in[11];
  const void* gms  = d_in[12];

  const int N = in_sizes[1];
  const int E = in_sizes[2] / 2;
  const int T = E + N;
  const int* srcp = eidx;
  const int* dstp = eidx + E;

  // workspace carve (~74 MB)
  char* p = (char*)d_ws;
  float* x  = (float*)p; p += (size_t)N*64*4;
  float* g  = (float*)p; p += (size_t)N*64*4;
  int* deg  = (int*)p;   p += ((size_t)N*4 + 63) & ~63ull;
  int* off  = (int*)p;   p += ((size_t)N*4 + 63) & ~63ull;
  int* cur  = (int*)p;   p += ((size_t)N*4 + 63) & ~63ull;
  int* pos  = (int*)p;   p += ((size_t)T*4 + 63) & ~63ull;
  int* csrc = (int*)p;   p += ((size_t)T*4 + 63) & ~63ull;
  float* acsr = (float*)p; p += ((size_t)T*4 + 63) & ~63ull;
  int* partial = (int*)p; p += 4096;
  float* stats = (float*)p; p += 4*1024*4;   // 4 layers x 8 banks x 128 floats
  float* pf = (float*)p; p += 8192;          // fp32 params [5][4][64]
  int* flag = (int*)p;   p += 64;

  const size_t x_base = 0;
  const size_t h_base = (size_t)N*64;
  const size_t a_base = (size_t)2*N*64;
  const float invN = 1.0f/(float)N;

  k_detect<<<1, 64, 0, stream>>>((const uint32_t*)xf, flag);
  k_params<<<1, 256, 0, stream>>>(att, cb, gw, gb, gms, flag, pf);
  k_encoder<<<2048, 256, 0, stream>>>(xf, ids, emb, win, bin, x, flag, N);

  k_deg_init <<<(N+255)/256, 256, 0, stream>>>(deg, stats, N);
  k_deg_count<<<(E+255)/256, 256, 0, stream>>>(dstp, deg, E);
  const int nchunks = (N + 1023) / 1024;
  k_scan_partial<<<nchunks, 256, 0, stream>>>(deg, partial, N);
  k_scan_final  <<<nchunks, 256, 0, stream>>>(deg, partial, off, cur, N, nchunks);
  k_scatter     <<<(T+255)/256, 256, 0, stream>>>(srcp, dstp, cur, pos, csrc, E, N);

  for(int l = 0; l < 4; l++){
    // linear of layer l; also applies GN of layer l-1 and emits its h/alpha
    k_linear<<<2048, 256, 0, stream>>>(x, lw, lb, g, stats, pf,
                                       d_out, acsr, pos, h_base,
                                       a_base + (size_t)(l-1)*T,
                                       flag, l, N, T, invN);
    k_gat<<<(N+3)/4, 256, 0, stream>>>(g, off, deg, csrc, pf, x,
                                       acsr, stats, l, N);
  }
  k_gn_final<<<1024, 256, 0, stream>>>(x, stats, pf, d_out,
                                       acsr, pos, x_base, h_base,
                                       a_base + (size_t)3*T, flag, N, T, invN);
}